// Round 1
// baseline (752.149 us; speedup 1.0000x reference)
//
#include <hip/hip_runtime.h>

#define B_SZ 1024
#define T_SZ 128
#define HID 512
#define LAB 100

// ---- d_ws layout (byte offsets) ----
#define OFF_X     0u          // int[262144]          1 MB
#define OFF_WH    1048576u    // ushort[262144]       512 KB
#define OFF_LEN   1572864u    // ushort[96000]
#define OFF_IPD   1764864u    // ushort[16384]
#define OFF_FC2   1797632u    // ushort[51200]
#define OFF_X2H   1900032u    // ushort[65536]        128 KB
#define OFF_FC2B  2031104u    // float[100] (+pad)
#define OFF_XIN   2097152u    // ushort[128][64][16][512] = 128 MB
#define WS_NEED   136314880u

typedef __attribute__((ext_vector_type(8))) short short8;
typedef __attribute__((ext_vector_type(4))) float float4v;
typedef __attribute__((ext_vector_type(4))) unsigned short us4;
typedef __attribute__((ext_vector_type(8))) __bf16 bf8_t;
typedef unsigned long long ull;

__device__ __attribute__((aligned(16))) unsigned char g_blob[WS_NEED]; // fallback only

__device__ __forceinline__ float bf2f(unsigned short u) {
    union { unsigned int i; float f; } z; z.i = ((unsigned int)u) << 16; return z.f;
}
__device__ __forceinline__ unsigned short f2bf(float f) {
    union { float f; unsigned int i; } z; z.f = f;
    unsigned int r = z.i + 0x7FFFu + ((z.i >> 16) & 1u);
    return (unsigned short)(r >> 16);
}
__device__ __forceinline__ float4v mfma16(short8 a, short8 b, float4v c) {
    return __builtin_amdgcn_mfma_f32_16x16x32_bf16(
        __builtin_bit_cast(bf8_t, a), __builtin_bit_cast(bf8_t, b), c, 0, 0, 0);
}

__global__ void conv_x_kernel(const int* __restrict__ xi, int* __restrict__ xo) {
    __shared__ int is64;
    if (threadIdx.x == 0) {
        int nz = 0;
        for (int j = 1; j < 64; j += 2) nz |= xi[j];
        is64 = (nz == 0) ? 1 : 0;
    }
    __syncthreads();
    const int n = B_SZ * T_SZ * 2;
    const int i64 = is64;
    for (int i = blockIdx.x * blockDim.x + threadIdx.x; i < n; i += gridDim.x * blockDim.x) {
        int v = i64 ? xi[2 * i] : xi[i];
        v = v < 0 ? 0 : (v > 255 ? 255 : v);
        xo[i] = v;
    }
}

__global__ void conv_floats_kernel(const float* __restrict__ len_e, const float* __restrict__ ipd_e,
                                   const float* __restrict__ h2h, const float* __restrict__ fc2,
                                   const float* __restrict__ x2h, const float* __restrict__ fc2b,
                                   unsigned short* __restrict__ o_len, unsigned short* __restrict__ o_ipd,
                                   unsigned short* __restrict__ o_wh, unsigned short* __restrict__ o_fc2,
                                   unsigned short* __restrict__ o_x2h, float* __restrict__ o_fc2b) {
    const int N0 = 96000, N1 = 16384, N2 = 262144, N3 = 51200, N4 = 65536, N5 = 100;
    const int total = N0 + N1 + N2 + N3 + N4 + N5;
    for (int i = blockIdx.x * blockDim.x + threadIdx.x; i < total; i += gridDim.x * blockDim.x) {
        int j = i;
        if (j < N0) { o_len[j] = f2bf(len_e[j]); continue; }
        j -= N0;
        if (j < N1) { o_ipd[j] = f2bf(ipd_e[j]); continue; }
        j -= N1;
        if (j < N2) { o_wh[j] = f2bf(h2h[j]); continue; }
        j -= N2;
        if (j < N3) { o_fc2[j] = f2bf(fc2[j]); continue; }
        j -= N3;
        if (j < N4) { o_x2h[j] = f2bf(x2h[j]); continue; }
        j -= N4;
        o_fc2b[j] = fc2b[j];
    }
}

// ---------------------------------------------------------------------------
// xin_kernel: xin[t][g][m][n] = (feats @ fc1^T + fc1_b) @ x2h^T + x2h_b + h2h_b
// 1024 blocks (t x 8 b-groups of 128 rows) x 256 threads. (unchanged, proven)
// ---------------------------------------------------------------------------
__launch_bounds__(256)
__global__ void xin_kernel(const int* __restrict__ w_x,
                           const unsigned short* __restrict__ w_len,
                           const unsigned short* __restrict__ w_ipd,
                           const float* __restrict__ fc1w, const float* __restrict__ fc1b,
                           const unsigned short* __restrict__ w_x2h,
                           const float* __restrict__ x2hb, const float* __restrict__ h2hb,
                           unsigned short* __restrict__ w_xin) {
    extern __shared__ unsigned short sm[];
    unsigned short* fT   = sm;
    unsigned short* fc1L = sm + 128 * 136;
    unsigned short* rT   = sm + 2 * 128 * 136;

    const int tid  = threadIdx.x;
    const int wv   = tid >> 6;
    const int ln   = tid & 63;
    const int mcol = ln & 15;
    const int q    = ln >> 4;
    const int t    = blockIdx.x >> 3;
    const int bg   = blockIdx.x & 7;

    {
        int row = tid >> 1, c = tid & 1;
        int idx = w_x[(bg * 128 + row) * 256 + t * 2 + c];
        const uint4* s4 = (const uint4*)((c ? w_ipd : w_len) + idx * 64);
        uint4* dst = (uint4*)&fT[row * 136 + c * 64];
#pragma unroll
        for (int i = 0; i < 8; i++) dst[i] = s4[i];
    }
#pragma unroll
    for (int it = 0; it < 8; it++) {
        int chunk = it * 256 + tid;
        int r = chunk >> 4, c8 = chunk & 15;
        const float* s = fc1w + r * 128 + c8 * 8;
        us4 a = { f2bf(s[0]), f2bf(s[1]), f2bf(s[2]), f2bf(s[3]) };
        us4 b = { f2bf(s[4]), f2bf(s[5]), f2bf(s[6]), f2bf(s[7]) };
        *(us4*)&fc1L[r * 136 + c8 * 8]     = a;
        *(us4*)&fc1L[r * 136 + c8 * 8 + 4] = b;
    }
    __syncthreads();

    for (int mt = 0; mt < 8; mt++) {
        float4v acc[2] = {{0.f,0.f,0.f,0.f},{0.f,0.f,0.f,0.f}};
#pragma unroll
        for (int kt = 0; kt < 4; kt++) {
            short8 bf = *(const short8*)&fT[(mt * 16 + mcol) * 136 + kt * 32 + q * 8];
#pragma unroll
            for (int u = 0; u < 2; u++) {
                int ntp = wv + u * 4;
                short8 fa = *(const short8*)&fc1L[(ntp * 16 + mcol) * 136 + kt * 32 + q * 8];
                acc[u] = mfma16(fa, bf, acc[u]);
            }
        }
#pragma unroll
        for (int u = 0; u < 2; u++) {
            int ntp = wv + u * 4;
            unsigned short o[4];
#pragma unroll
            for (int r = 0; r < 4; r++)
                o[r] = f2bf(acc[u][r] + fc1b[ntp * 16 + q * 4 + r]);
            us4 v = { o[0], o[1], o[2], o[3] };
            *(us4*)&rT[(mt * 16 + mcol) * 136 + ntp * 16 + q * 4] = v;
        }
    }
    __syncthreads();

    float bias[8][4];
#pragma unroll
    for (int i = 0; i < 8; i++)
#pragma unroll
        for (int r = 0; r < 4; r++) {
            int n = (wv * 8 + i) * 16 + q * 4 + r;
            bias[i][r] = x2hb[n] + h2hb[n];
        }
    for (int mt = 0; mt < 8; mt++) {
        float4v acc[8];
#pragma unroll
        for (int i = 0; i < 8; i++) acc[i] = (float4v){0.f,0.f,0.f,0.f};
#pragma unroll
        for (int kt = 0; kt < 4; kt++) {
            short8 bf = *(const short8*)&rT[(mt * 16 + mcol) * 136 + kt * 32 + q * 8];
#pragma unroll
            for (int i = 0; i < 8; i++) {
                int n16 = (wv * 8 + i) * 16;
                short8 fa = *(const short8*)(w_x2h + (n16 + mcol) * 128 + kt * 32 + q * 8);
                acc[i] = mfma16(fa, bf, acc[i]);
            }
        }
        int m = mt * 16 + mcol;
        int g = bg * 8 + (m >> 4), mm = m & 15;
#pragma unroll
        for (int i = 0; i < 8; i++) {
            int n0i = (wv * 8 + i) * 16 + q * 4;
            us4 v = { f2bf(acc[i][0] + bias[i][0]), f2bf(acc[i][1] + bias[i][1]),
                      f2bf(acc[i][2] + bias[i][2]), f2bf(acc[i][3] + bias[i][3]) };
            *(us4*)&w_xin[((t * 64 + g) * 16 + mm) * 512 + n0i] = v;
        }
    }
}

// ---------------------------------------------------------------------------
// RNN v2: 64 blocks x 512 threads (8 waves, 2/SIMD).
// ALL of Wh (16 kt) lives in registers: 4 nt x 16 kt x 4 VGPR = 256 regs/wave
// (2 waves/SIMD -> 768 of 2048-reg pool incl. acc; MFMA sources A from AGPR).
// LDS = ONLY the h double-buffer (32 KB). This halves the per-step LDS read
// traffic (256 KB -> 128 KB), which was the dominant shared-pipe cost.
// tanh: no clamp (exp saturates correctly), approx rcp instead of precise div.
// LDS offsets (XOR-swizzled) hoisted out of the t-loop.
// ---------------------------------------------------------------------------
__launch_bounds__(512, 2)
__global__ void rnn_kernel(const unsigned short* __restrict__ w_wh,
                           const unsigned short* __restrict__ w_xin,
                           const unsigned short* __restrict__ w_fc2,
                           const float* __restrict__ w_fc2b,
                           float* __restrict__ out) {
    extern __shared__ unsigned short sm2[];
    unsigned short* sH = sm2;            // h dbuf: 2 x 8192 ushorts (32 KB)

    const int tid  = threadIdx.x;
    const int wv   = tid >> 6;           // 0..7
    const int ln   = tid & 63;
    const int mcol = ln & 15;            // batch within block
    const int q    = ln >> 4;
    const int g    = blockIdx.x;
    const int b0   = g * 16;
    const int n0   = wv * 64;            // wave owns hidden rows n0..n0+63

    // ---- zero h buffer 0 (8192 ushorts) ----
    {
        uint4 z = {0, 0, 0, 0};
        *(uint4*)&sH[tid * 8] = z;
        *(uint4*)&sH[(512 + tid) * 8] = z;
    }

    // ---- ALL of Wh into registers: 64 frags = 256 VGPR/AGPR ----
    short8 whr[4][16];
#pragma unroll
    for (int nt = 0; nt < 4; nt++)
#pragma unroll
        for (int kt = 0; kt < 16; kt++)
            whr[nt][kt] = *(const short8*)(w_wh + (n0 + nt * 16 + mcol) * 512 + kt * 32 + q * 8);

    // ---- hoisted swizzled LDS offsets (ushort units) ----
    int bh_off[16];
#pragma unroll
    for (int kt = 0; kt < 16; kt++)
        bh_off[kt] = mcol * 512 + (((kt * 4 + q) ^ mcol) & 63) * 8;
    int hw_off[4];
#pragma unroll
    for (int nt = 0; nt < 4; nt++) {
        int n = n0 + nt * 16 + q * 4;
        hw_off[nt] = mcol * 512 + (((n >> 3) ^ mcol) & 63) * 8 + (n & 7);
    }

    // ---- xin prefetch (t=0) ----
    const unsigned short* xin_b = w_xin + (g * 16 + mcol) * 512 + n0 + q * 4;
    us4 xq[4];
#pragma unroll
    for (int nt = 0; nt < 4; nt++)
        xq[nt] = *(const us4*)(xin_b + nt * 16);

    __syncthreads();

    for (int t = 0; t < T_SZ; t++) {
        const int rb = (t & 1) << 13;    // read-buffer base (ushort idx)
        const int wb = rb ^ 8192;        // write-buffer base

        // ---- acc init from prefetched xin ----
        float4v acc[4];
#pragma unroll
        for (int nt = 0; nt < 4; nt++) {
            acc[nt][0] = bf2f(xq[nt][0]); acc[nt][1] = bf2f(xq[nt][1]);
            acc[nt][2] = bf2f(xq[nt][2]); acc[nt][3] = bf2f(xq[nt][3]);
        }
        // ---- prefetch xin(t+1) (hidden under MFMA phase) ----
        if (t + 1 < T_SZ) {
            const unsigned short* xb = xin_b + (ull)(t + 1) * 64 * 16 * 512;
#pragma unroll
            for (int nt = 0; nt < 4; nt++)
                xq[nt] = *(const us4*)(xb + nt * 16);
        }

        // ---- all 16 kt: Wh from regs, h from LDS (16 ds_read_b128/wave) ----
#pragma unroll
        for (int kt = 0; kt < 16; kt++) {
            short8 bh = *(const short8*)&sH[rb + bh_off[kt]];
#pragma unroll
            for (int nt = 0; nt < 4; nt++)
                acc[nt] = mfma16(whr[nt][kt], bh, acc[nt]);
        }

        // ---- fast tanh -> bf16, write h(t+1) into other buffer ----
#pragma unroll
        for (int nt = 0; nt < 4; nt++) {
            unsigned short o[4];
#pragma unroll
            for (int r = 0; r < 4; r++) {
                // tanh(v) = 1 - 2/(e^{2v}+1); exp overflow/underflow saturates
                // to +-1 correctly, so no clamp. Approx rcp: ~1 ulp f32,
                // far below bf16 quantization.
                float e  = __expf(2.0f * acc[nt][r]);
                float th = 1.0f - 2.0f * __builtin_amdgcn_rcpf(e + 1.0f);
                o[r] = f2bf(th);
            }
            us4 v4 = { o[0], o[1], o[2], o[3] };
            *(us4*)&sH[wb + hw_off[nt]] = v4;
        }
        __syncthreads();   // h(t+1) visible to all waves before next step
    }

    // final h is in buffer 0 (T_SZ even)
    // ---- fc2 epilogue: waves 0..6 cover 112 >= 100 labels ----
    if (wv < 7) {
        int lA = wv * 16 + mcol; if (lA > 99) lA = 99;
        float4v a2 = {0.f, 0.f, 0.f, 0.f};
#pragma unroll 4
        for (int kt = 0; kt < 16; kt++) {
            short8 fa = *(const short8*)(w_fc2 + lA * 512 + kt * 32 + q * 8);
            short8 bh = *(const short8*)&sH[bh_off[kt]];
            a2 = mfma16(fa, bh, a2);
        }
#pragma unroll
        for (int r = 0; r < 4; r++) {
            int l = wv * 16 + q * 4 + r;
            if (l < 100) out[(b0 + mcol) * 100 + l] = a2[r] + w_fc2b[l];
        }
    }
}

extern "C" void kernel_launch(void* const* d_in, const int* in_sizes, int n_in,
                              void* d_out, int out_size, void* d_ws, size_t ws_size,
                              hipStream_t stream) {
    unsigned char* base = (unsigned char*)d_ws;
    if (ws_size < (size_t)WS_NEED) {
        void* p = nullptr;
        hipGetSymbolAddress(&p, HIP_SYMBOL(g_blob));
        base = (unsigned char*)p;
    }
    int*            w_x    = (int*)(base + OFF_X);
    unsigned short* w_wh   = (unsigned short*)(base + OFF_WH);
    unsigned short* w_len  = (unsigned short*)(base + OFF_LEN);
    unsigned short* w_ipd  = (unsigned short*)(base + OFF_IPD);
    unsigned short* w_fc2  = (unsigned short*)(base + OFF_FC2);
    unsigned short* w_x2h  = (unsigned short*)(base + OFF_X2H);
    float*          w_fc2b = (float*)(base + OFF_FC2B);
    unsigned short* w_xin  = (unsigned short*)(base + OFF_XIN);

    static bool attr_set = false;
    if (!attr_set) {
        hipFuncSetAttribute((const void*)xin_kernel,
                            hipFuncAttributeMaxDynamicSharedMemorySize, 3 * 128 * 136 * 2);
        hipFuncSetAttribute((const void*)rnn_kernel,
                            hipFuncAttributeMaxDynamicSharedMemorySize, 32768);
        attr_set = true;
    }

    conv_x_kernel<<<256, 256, 0, stream>>>((const int*)d_in[0], w_x);
    conv_floats_kernel<<<1024, 256, 0, stream>>>(
        (const float*)d_in[1], (const float*)d_in[2], (const float*)d_in[7],
        (const float*)d_in[9], (const float*)d_in[5], (const float*)d_in[10],
        w_len, w_ipd, w_wh, w_fc2, w_x2h, w_fc2b);
    xin_kernel<<<1024, 256, 3 * 128 * 136 * 2, stream>>>(
        w_x, w_len, w_ipd,
        (const float*)d_in[3], (const float*)d_in[4],
        w_x2h, (const float*)d_in[6], (const float*)d_in[8],
        w_xin);
    rnn_kernel<<<64, 512, 32768, stream>>>(
        w_wh, w_xin, w_fc2, w_fc2b, (float*)d_out);
}

// Round 2
// 401.219 us; speedup vs baseline: 1.8747x; 1.8747x over previous
//
#include <hip/hip_runtime.h>

#define B_SZ 1024
#define T_SZ 128
#define HID 512
#define LAB 100

// ---- d_ws layout (byte offsets) ----
#define OFF_X     0u          // int[262144]          1 MB
#define OFF_WH    1048576u    // ushort[262144]       512 KB
#define OFF_LEN   1572864u    // ushort[96000]
#define OFF_IPD   1764864u    // ushort[16384]
#define OFF_FC2   1797632u    // ushort[51200]
#define OFF_X2H   1900032u    // ushort[65536]        128 KB
#define OFF_FC2B  2031104u    // float[100] (+pad)
#define OFF_XIN   2097152u    // ushort[128][64][16][512] = 128 MB
#define WS_NEED   136314880u

typedef __attribute__((ext_vector_type(8))) short short8;
typedef __attribute__((ext_vector_type(4))) float float4v;
typedef __attribute__((ext_vector_type(4))) unsigned short us4;
typedef __attribute__((ext_vector_type(8))) __bf16 bf8_t;
typedef unsigned long long ull;

__device__ __attribute__((aligned(16))) unsigned char g_blob[WS_NEED]; // fallback only

__device__ __forceinline__ float bf2f(unsigned short u) {
    union { unsigned int i; float f; } z; z.i = ((unsigned int)u) << 16; return z.f;
}
__device__ __forceinline__ unsigned short f2bf(float f) {
    union { float f; unsigned int i; } z; z.f = f;
    unsigned int r = z.i + 0x7FFFu + ((z.i >> 16) & 1u);
    return (unsigned short)(r >> 16);
}
__device__ __forceinline__ float4v mfma16(short8 a, short8 b, float4v c) {
    return __builtin_amdgcn_mfma_f32_16x16x32_bf16(
        __builtin_bit_cast(bf8_t, a), __builtin_bit_cast(bf8_t, b), c, 0, 0, 0);
}

__global__ void conv_x_kernel(const int* __restrict__ xi, int* __restrict__ xo) {
    __shared__ int is64;
    if (threadIdx.x == 0) {
        int nz = 0;
        for (int j = 1; j < 64; j += 2) nz |= xi[j];
        is64 = (nz == 0) ? 1 : 0;
    }
    __syncthreads();
    const int n = B_SZ * T_SZ * 2;
    const int i64 = is64;
    for (int i = blockIdx.x * blockDim.x + threadIdx.x; i < n; i += gridDim.x * blockDim.x) {
        int v = i64 ? xi[2 * i] : xi[i];
        v = v < 0 ? 0 : (v > 255 ? 255 : v);
        xo[i] = v;
    }
}

__global__ void conv_floats_kernel(const float* __restrict__ len_e, const float* __restrict__ ipd_e,
                                   const float* __restrict__ h2h, const float* __restrict__ fc2,
                                   const float* __restrict__ x2h, const float* __restrict__ fc2b,
                                   unsigned short* __restrict__ o_len, unsigned short* __restrict__ o_ipd,
                                   unsigned short* __restrict__ o_wh, unsigned short* __restrict__ o_fc2,
                                   unsigned short* __restrict__ o_x2h, float* __restrict__ o_fc2b) {
    const int N0 = 96000, N1 = 16384, N2 = 262144, N3 = 51200, N4 = 65536, N5 = 100;
    const int total = N0 + N1 + N2 + N3 + N4 + N5;
    for (int i = blockIdx.x * blockDim.x + threadIdx.x; i < total; i += gridDim.x * blockDim.x) {
        int j = i;
        if (j < N0) { o_len[j] = f2bf(len_e[j]); continue; }
        j -= N0;
        if (j < N1) { o_ipd[j] = f2bf(ipd_e[j]); continue; }
        j -= N1;
        if (j < N2) { o_wh[j] = f2bf(h2h[j]); continue; }
        j -= N2;
        if (j < N3) { o_fc2[j] = f2bf(fc2[j]); continue; }
        j -= N3;
        if (j < N4) { o_x2h[j] = f2bf(x2h[j]); continue; }
        j -= N4;
        o_fc2b[j] = fc2b[j];
    }
}

// ---------------------------------------------------------------------------
// xin_kernel: xin[t][g][m][n] = (feats @ fc1^T + fc1_b) @ x2h^T + x2h_b + h2h_b
// 1024 blocks (t x 8 b-groups of 128 rows) x 256 threads. (unchanged, proven)
// ---------------------------------------------------------------------------
__launch_bounds__(256)
__global__ void xin_kernel(const int* __restrict__ w_x,
                           const unsigned short* __restrict__ w_len,
                           const unsigned short* __restrict__ w_ipd,
                           const float* __restrict__ fc1w, const float* __restrict__ fc1b,
                           const unsigned short* __restrict__ w_x2h,
                           const float* __restrict__ x2hb, const float* __restrict__ h2hb,
                           unsigned short* __restrict__ w_xin) {
    extern __shared__ unsigned short sm[];
    unsigned short* fT   = sm;
    unsigned short* fc1L = sm + 128 * 136;
    unsigned short* rT   = sm + 2 * 128 * 136;

    const int tid  = threadIdx.x;
    const int wv   = tid >> 6;
    const int ln   = tid & 63;
    const int mcol = ln & 15;
    const int q    = ln >> 4;
    const int t    = blockIdx.x >> 3;
    const int bg   = blockIdx.x & 7;

    {
        int row = tid >> 1, c = tid & 1;
        int idx = w_x[(bg * 128 + row) * 256 + t * 2 + c];
        const uint4* s4 = (const uint4*)((c ? w_ipd : w_len) + idx * 64);
        uint4* dst = (uint4*)&fT[row * 136 + c * 64];
#pragma unroll
        for (int i = 0; i < 8; i++) dst[i] = s4[i];
    }
#pragma unroll
    for (int it = 0; it < 8; it++) {
        int chunk = it * 256 + tid;
        int r = chunk >> 4, c8 = chunk & 15;
        const float* s = fc1w + r * 128 + c8 * 8;
        us4 a = { f2bf(s[0]), f2bf(s[1]), f2bf(s[2]), f2bf(s[3]) };
        us4 b = { f2bf(s[4]), f2bf(s[5]), f2bf(s[6]), f2bf(s[7]) };
        *(us4*)&fc1L[r * 136 + c8 * 8]     = a;
        *(us4*)&fc1L[r * 136 + c8 * 8 + 4] = b;
    }
    __syncthreads();

    for (int mt = 0; mt < 8; mt++) {
        float4v acc[2] = {{0.f,0.f,0.f,0.f},{0.f,0.f,0.f,0.f}};
#pragma unroll
        for (int kt = 0; kt < 4; kt++) {
            short8 bf = *(const short8*)&fT[(mt * 16 + mcol) * 136 + kt * 32 + q * 8];
#pragma unroll
            for (int u = 0; u < 2; u++) {
                int ntp = wv + u * 4;
                short8 fa = *(const short8*)&fc1L[(ntp * 16 + mcol) * 136 + kt * 32 + q * 8];
                acc[u] = mfma16(fa, bf, acc[u]);
            }
        }
#pragma unroll
        for (int u = 0; u < 2; u++) {
            int ntp = wv + u * 4;
            unsigned short o[4];
#pragma unroll
            for (int r = 0; r < 4; r++)
                o[r] = f2bf(acc[u][r] + fc1b[ntp * 16 + q * 4 + r]);
            us4 v = { o[0], o[1], o[2], o[3] };
            *(us4*)&rT[(mt * 16 + mcol) * 136 + ntp * 16 + q * 4] = v;
        }
    }
    __syncthreads();

    float bias[8][4];
#pragma unroll
    for (int i = 0; i < 8; i++)
#pragma unroll
        for (int r = 0; r < 4; r++) {
            int n = (wv * 8 + i) * 16 + q * 4 + r;
            bias[i][r] = x2hb[n] + h2hb[n];
        }
    for (int mt = 0; mt < 8; mt++) {
        float4v acc[8];
#pragma unroll
        for (int i = 0; i < 8; i++) acc[i] = (float4v){0.f,0.f,0.f,0.f};
#pragma unroll
        for (int kt = 0; kt < 4; kt++) {
            short8 bf = *(const short8*)&rT[(mt * 16 + mcol) * 136 + kt * 32 + q * 8];
#pragma unroll
            for (int i = 0; i < 8; i++) {
                int n16 = (wv * 8 + i) * 16;
                short8 fa = *(const short8*)(w_x2h + (n16 + mcol) * 128 + kt * 32 + q * 8);
                acc[i] = mfma16(fa, bf, acc[i]);
            }
        }
        int m = mt * 16 + mcol;
        int g = bg * 8 + (m >> 4), mm = m & 15;
#pragma unroll
        for (int i = 0; i < 8; i++) {
            int n0i = (wv * 8 + i) * 16 + q * 4;
            us4 v = { f2bf(acc[i][0] + bias[i][0]), f2bf(acc[i][1] + bias[i][1]),
                      f2bf(acc[i][2] + bias[i][2]), f2bf(acc[i][3] + bias[i][3]) };
            *(us4*)&w_xin[((t * 64 + g) * 16 + mm) * 512 + n0i] = v;
        }
    }
}

// ---------------------------------------------------------------------------
// RNN v3: 64 blocks x 512 threads (8 waves, 2/SIMD). Round-0 proven memory
// structure: Wh kt0..11 in 192 VGPRs, kt12..15 in 128 KB LDS (swizzled);
// h double-buffered bf16 (2x16 KB) -> ONE barrier/step. VALU cuts:
//   * fast tanh: 1 - 2*rcp(e^{2v}+1), no clamp (exp saturates correctly),
//     approx rcp (validated round 1: identical absmax)
//   * strength-reduced XOR-swizzle addressing: ((k^mcol)&63) decomposed over
//     disjoint bit fields -> 4 shared ej[] regs + 2 base regs, zero per-kt VALU
//   * running xin pointer instead of per-step 64-bit multiply
// Register budget (2 waves/SIMD = 256 unified): 192 whr + 16 acc + 8 xq
// + ~14 addr = ~230. NO spills expected (WRITE_SIZE must stay ~400 KB).
// ---------------------------------------------------------------------------
__launch_bounds__(512, 2)
__global__ void rnn_kernel(const unsigned short* __restrict__ w_wh,
                           const unsigned short* __restrict__ w_xin,
                           const unsigned short* __restrict__ w_fc2,
                           const float* __restrict__ w_fc2b,
                           float* __restrict__ out) {
    extern __shared__ unsigned short sm2[];
    unsigned short* sA = sm2;            // Wh k 384..511: 65536 ushorts (128 KB)
    unsigned short* sH = sm2 + 65536;    // h dbuf: 2 x 8192 ushorts (32 KB)

    const int tid  = threadIdx.x;
    const int wv   = tid >> 6;           // 0..7
    const int ln   = tid & 63;
    const int mcol = ln & 15;            // batch col within block
    const int q    = ln >> 4;
    const int g    = blockIdx.x;
    const int b0   = g * 16;
    const int n0   = wv * 64;            // wave owns hidden rows n0..n0+63

    // ---- stage Wh kt 12..15 into LDS (swizzled) ----
    for (int it = 0; it < 16; it++) {
        int chunk = it * 512 + tid;          // 0..8191
        int r = chunk >> 4, c = chunk & 15;
        uint4 v = *(const uint4*)(w_wh + r * 512 + 384 + c * 8);
        *(uint4*)&sA[r * 128 + ((c ^ (r & 15)) & 15) * 8] = v;
    }
    // ---- zero h buffer 0 ----
    {
        uint4 z = {0, 0, 0, 0};
        *(uint4*)&sH[tid * 8] = z;
        *(uint4*)&sH[(512 + tid) * 8] = z;
    }
    // ---- Wh kt 0..11 into registers: 48 frags = 192 VGPRs ----
    short8 whr[4][12];
#pragma unroll
    for (int nt = 0; nt < 4; nt++)
#pragma unroll
        for (int kt = 0; kt < 12; kt++)
            whr[nt][kt] = *(const short8*)(w_wh + (n0 + nt * 16 + mcol) * 512 + kt * 32 + q * 8);

    // ---- strength-reduced swizzle offsets (ushort units) ----
    // ((kt*4+q)^mcol)&63 = (kt>>2)*16 + ((kt&3)*4 ^ (mcol&12)) + (q ^ (mcol&3))
    // (disjoint bit fields), so per-kt address math folds into immediates.
    const int qlo = (q ^ (mcol & 3)) * 8;
    int ej[4];
#pragma unroll
    for (int j = 0; j < 4; j++)
        ej[j] = ((j * 4) ^ (mcol & 12)) * 8;
    const int base_b = mcol * 512 + qlo;          // h-read base
    const int fbase  = (n0 + mcol) * 128 + qlo;   // sA-read base
    int hw_off[4];
#pragma unroll
    for (int nt = 0; nt < 4; nt++) {
        int n = n0 + nt * 16 + q * 4;
        hw_off[nt] = mcol * 512 + (((n >> 3) ^ mcol) & 63) * 8 + (n & 7);
    }

    // ---- xin prefetch (t=0); running pointer, stride = 64*16*512 ushorts ----
    const unsigned short* xin_p = w_xin + (g * 16 + mcol) * 512 + n0 + q * 4;
    us4 xq[4];
#pragma unroll
    for (int nt = 0; nt < 4; nt++)
        xq[nt] = *(const us4*)(xin_p + nt * 16);

    __syncthreads();

    for (int t = 0; t < T_SZ; t++) {
        const unsigned short* hRd = sH + ((t & 1) << 13);
        unsigned short* hWr = sH + (((t + 1) & 1) << 13);

        // ---- acc init from prefetched xin ----
        float4v acc[4];
#pragma unroll
        for (int nt = 0; nt < 4; nt++) {
            acc[nt][0] = bf2f(xq[nt][0]); acc[nt][1] = bf2f(xq[nt][1]);
            acc[nt][2] = bf2f(xq[nt][2]); acc[nt][3] = bf2f(xq[nt][3]);
        }
        // ---- prefetch xin(t+1) (hidden under MFMA phase) ----
        xin_p += 64 * 16 * 512;
        if (t + 1 < T_SZ) {
#pragma unroll
            for (int nt = 0; nt < 4; nt++)
                xq[nt] = *(const us4*)(xin_p + nt * 16);
        }

        // ---- Wh MFMAs: kt 0..11 from regs ----
#pragma unroll
        for (int kt = 0; kt < 12; kt++) {
            short8 bh = *(const short8*)&hRd[base_b + ej[kt & 3] + (kt >> 2) * 128];
#pragma unroll
            for (int nt = 0; nt < 4; nt++)
                acc[nt] = mfma16(whr[nt][kt], bh, acc[nt]);
        }
        // ---- kt 12..15 from LDS ----
#pragma unroll
        for (int j = 0; j < 4; j++) {
            short8 bh = *(const short8*)&hRd[base_b + ej[j] + 384];
#pragma unroll
            for (int nt = 0; nt < 4; nt++) {
                short8 fa = *(const short8*)&sA[fbase + nt * 2048 + ej[j]];
                acc[nt] = mfma16(fa, bh, acc[nt]);
            }
        }

        // ---- fast tanh -> bf16, write h(t+1) into other buffer ----
#pragma unroll
        for (int nt = 0; nt < 4; nt++) {
            unsigned short o[4];
#pragma unroll
            for (int r = 0; r < 4; r++) {
                // tanh(v) = 1 - 2/(e^{2v}+1); exp inf/0 saturates to +-1,
                // so no clamp. Approx rcp ~1 ulp << bf16 quantization.
                float e  = __expf(2.0f * acc[nt][r]);
                float th = 1.0f - 2.0f * __builtin_amdgcn_rcpf(e + 1.0f);
                o[r] = f2bf(th);
            }
            us4 v4 = { o[0], o[1], o[2], o[3] };
            *(us4*)&hWr[hw_off[nt]] = v4;
        }
        __syncthreads();   // h(t+1) visible to all waves before next step
    }

    // final h is in buffer 0 (T_SZ even)
    unsigned short* hF = sH;

    // ---- fc2 epilogue: waves 0..6 cover 112 >= 100 labels ----
    if (wv < 7) {
        int lA = wv * 16 + mcol; if (lA > 99) lA = 99;
        float4v a2 = {0.f, 0.f, 0.f, 0.f};
#pragma unroll
        for (int kt = 0; kt < 16; kt++) {
            short8 fa = *(const short8*)(w_fc2 + lA * 512 + kt * 32 + q * 8);
            short8 bh = *(const short8*)&hF[base_b + ej[kt & 3] + (kt >> 2) * 128];
            a2 = mfma16(fa, bh, a2);
        }
#pragma unroll
        for (int r = 0; r < 4; r++) {
            int l = wv * 16 + q * 4 + r;
            if (l < 100) out[(b0 + mcol) * 100 + l] = a2[r] + w_fc2b[l];
        }
    }
}

extern "C" void kernel_launch(void* const* d_in, const int* in_sizes, int n_in,
                              void* d_out, int out_size, void* d_ws, size_t ws_size,
                              hipStream_t stream) {
    unsigned char* base = (unsigned char*)d_ws;
    if (ws_size < (size_t)WS_NEED) {
        void* p = nullptr;
        hipGetSymbolAddress(&p, HIP_SYMBOL(g_blob));
        base = (unsigned char*)p;
    }
    int*            w_x    = (int*)(base + OFF_X);
    unsigned short* w_wh   = (unsigned short*)(base + OFF_WH);
    unsigned short* w_len  = (unsigned short*)(base + OFF_LEN);
    unsigned short* w_ipd  = (unsigned short*)(base + OFF_IPD);
    unsigned short* w_fc2  = (unsigned short*)(base + OFF_FC2);
    unsigned short* w_x2h  = (unsigned short*)(base + OFF_X2H);
    float*          w_fc2b = (float*)(base + OFF_FC2B);
    unsigned short* w_xin  = (unsigned short*)(base + OFF_XIN);

    static bool attr_set = false;
    if (!attr_set) {
        hipFuncSetAttribute((const void*)xin_kernel,
                            hipFuncAttributeMaxDynamicSharedMemorySize, 3 * 128 * 136 * 2);
        hipFuncSetAttribute((const void*)rnn_kernel,
                            hipFuncAttributeMaxDynamicSharedMemorySize, 163840);
        attr_set = true;
    }

    conv_x_kernel<<<256, 256, 0, stream>>>((const int*)d_in[0], w_x);
    conv_floats_kernel<<<1024, 256, 0, stream>>>(
        (const float*)d_in[1], (const float*)d_in[2], (const float*)d_in[7],
        (const float*)d_in[9], (const float*)d_in[5], (const float*)d_in[10],
        w_len, w_ipd, w_wh, w_fc2, w_x2h, w_fc2b);
    xin_kernel<<<1024, 256, 3 * 128 * 136 * 2, stream>>>(
        w_x, w_len, w_ipd,
        (const float*)d_in[3], (const float*)d_in[4],
        w_x2h, (const float*)d_in[6], (const float*)d_in[8],
        w_xin);
    rnn_kernel<<<64, 512, 163840, stream>>>(
        w_wh, w_xin, w_fc2, w_fc2b, (float*)d_out);
}